// Round 4
// baseline (828.323 us; speedup 1.0000x reference)
//
#include <hip/hip_runtime.h>
#include <stdint.h>

typedef unsigned short u16;
typedef __bf16 bf16x8 __attribute__((ext_vector_type(8)));
typedef float f32x4 __attribute__((ext_vector_type(4)));
typedef uint32_t u32x4 __attribute__((ext_vector_type(4)));

// ---- problem constants (fixed by the reference) ----
constexpr int P_  = 4, B_ = 2, S_ = 2048, D_ = 2048;
constexpr int H_  = 16, HK_ = 4, DH_ = 128;
constexpr int M_  = P_ * B_ * S_;            // 16384 rows of hidden_states
constexpr int NQKV = (H_ + 2 * HK_) * DH_;   // 3072 fused QKV columns
constexpr int K_  = D_;                      // 2048

__device__ __forceinline__ float bf2f(u16 u) {
  union { unsigned int i; float f; } v; v.i = ((unsigned int)u) << 16; return v.f;
}
__device__ __forceinline__ u16 f2bf(float f) {
  union { float f; unsigned int i; } v; v.f = f;
  unsigned int r = v.i + 0x7fffu + ((v.i >> 16) & 1u);  // RNE
  return (u16)(r >> 16);
}
__device__ __forceinline__ uint32_t pkbf(float lo, float hi) {
  return (uint32_t)f2bf(lo) | ((uint32_t)f2bf(hi) << 16);
}

// ---------------------------------------------------------------------------
// Tiled transpose + fp32->bf16 convert: src fp32 (rows x cols) ->
// dst bf16 [dstOff + c*ld + r]
// ---------------------------------------------------------------------------
__global__ __launch_bounds__(256) void transpose_f32_bf16(
    const float* __restrict__ src, u16* __restrict__ dst,
    int rows, int cols, size_t dstOff, int ld) {
  __shared__ float tile[32][33];
  int c0 = blockIdx.x * 32, r0 = blockIdx.y * 32;
  int tx = threadIdx.x, ty = threadIdx.y;  // 32 x 8
#pragma unroll
  for (int i = 0; i < 32; i += 8)
    tile[ty + i][tx] = src[(size_t)(r0 + ty + i) * cols + (c0 + tx)];
  __syncthreads();
#pragma unroll
  for (int i = 0; i < 32; i += 8)
    dst[dstOff + (size_t)(c0 + ty + i) * ld + (r0 + tx)] = f2bf(tile[tx][ty + i]);
}

// concat bq|bk|bv (fp32) -> bias[3072] fp32
__global__ void build_bias(const float* __restrict__ bq, const float* __restrict__ bk,
                           const float* __restrict__ bv, float* __restrict__ bias) {
  int n = blockIdx.x * 256 + threadIdx.x;
  if (n < NQKV)
    bias[n] = (n < H_ * DH_) ? bq[n]
            : (n < H_ * DH_ + HK_ * DH_) ? bk[n - H_ * DH_]
            : bv[n - H_ * DH_ - HK_ * DH_];
}

// ---------------------------------------------------------------------------
// C(M x N) = A(M x K[lda]) * BT(N x K)^T + bias, fp32 accum, bf16 MFMA.
// A is fp32 when AF32 (converted during staging) else bf16.
// Output is fp32 when OUTF32 (d_out is float per reference dtype) else bf16.
// 128x128 block tile, BK=32, 4 waves (2x2), each wave 4x4 of 16x16x32 MFMA.
// LDS swizzle: physical slot s of row r holds global chunk s ^ ((r>>1)&3);
// fragment ds_read_b128 uses slot quad ^ ((tm>>1)&3).
// ---------------------------------------------------------------------------
template <bool AF32, bool OUTF32>
__global__ __launch_bounds__(256) void gemm_bt(
    const void* __restrict__ Av, int lda, const u16* __restrict__ BT,
    void* __restrict__ Cv, int N, int K, const float* __restrict__ bias) {
  __shared__ __align__(16) u16 As[128 * 32];
  __shared__ __align__(16) u16 Bs[128 * 32];

  const int tid  = threadIdx.x;
  const int wave = tid >> 6;
  const int lane = tid & 63;
  const int waveM = wave & 1, waveN = wave >> 1;

  const int mBase = blockIdx.y * 128;
  const int nBase = blockIdx.x * 128;

  // staging: lane covers row (l>>2) of a 16-row slab, phys slot (l&3),
  // sourcing global chunk cg = slot ^ ((row>>1)&3)
  const int l4 = lane >> 2;
  const int cg = (lane & 3) ^ ((lane >> 3) & 3);

  const float* agf0 = nullptr; const float* agf1 = nullptr;
  const u16*   agh0 = nullptr; const u16*   agh1 = nullptr;
  if (AF32) {
    agf0 = (const float*)Av + (size_t)(mBase + wave * 16 + l4) * lda + cg * 8;
    agf1 = agf0 + (size_t)64 * lda;
  } else {
    agh0 = (const u16*)Av + (size_t)(mBase + wave * 16 + l4) * lda + cg * 8;
    agh1 = agh0 + (size_t)64 * lda;
  }
  const u16* bg0 = BT + (size_t)(nBase + wave * 16 + l4) * K + cg * 8;
  const u16* bg1 = bg0 + (size_t)64 * K;
  u16* al0 = As + wave * 512 + lane * 8;
  u16* al1 = As + 2048 + wave * 512 + lane * 8;
  u16* bl0 = Bs + wave * 512 + lane * 8;
  u16* bl1 = Bs + 2048 + wave * 512 + lane * 8;

  // fragment read: row tm of each 16-row tile, quad selects k-chunk (swizzled)
  const int tm = lane & 15;
  const int quad = lane >> 4;
  const int rslot = quad ^ ((tm >> 1) & 3);
  const u16* aRead = As + (waveM * 64 + tm) * 32 + rslot * 8;
  const u16* bRead = Bs + (waveN * 64 + tm) * 32 + rslot * 8;

  f32x4 acc[4][4];
#pragma unroll
  for (int i = 0; i < 4; i++)
#pragma unroll
    for (int j = 0; j < 4; j++) acc[i][j] = (f32x4){0.f, 0.f, 0.f, 0.f};

  for (int k0 = 0; k0 < K; k0 += 32) {
    u32x4 ra0, ra1;
    if (AF32) {
      f32x4 lo0 = *(const f32x4*)(agf0 + k0);
      f32x4 hi0 = *(const f32x4*)(agf0 + k0 + 4);
      f32x4 lo1 = *(const f32x4*)(agf1 + k0);
      f32x4 hi1 = *(const f32x4*)(agf1 + k0 + 4);
      ra0 = (u32x4){pkbf(lo0[0], lo0[1]), pkbf(lo0[2], lo0[3]),
                    pkbf(hi0[0], hi0[1]), pkbf(hi0[2], hi0[3])};
      ra1 = (u32x4){pkbf(lo1[0], lo1[1]), pkbf(lo1[2], lo1[3]),
                    pkbf(hi1[0], hi1[1]), pkbf(hi1[2], hi1[3])};
    } else {
      ra0 = *(const u32x4*)(agh0 + k0);
      ra1 = *(const u32x4*)(agh1 + k0);
    }
    u32x4 rb0 = *(const u32x4*)(bg0 + k0);
    u32x4 rb1 = *(const u32x4*)(bg1 + k0);
    __syncthreads();  // prior iteration's LDS reads complete
    *(u32x4*)al0 = ra0;
    *(u32x4*)al1 = ra1;
    *(u32x4*)bl0 = rb0;
    *(u32x4*)bl1 = rb1;
    __syncthreads();  // tile visible to all waves

    bf16x8 af[4], bf[4];
#pragma unroll
    for (int i = 0; i < 4; i++) {
      af[i] = *(const bf16x8*)(aRead + i * 512);
      bf[i] = *(const bf16x8*)(bRead + i * 512);
    }
#pragma unroll
    for (int i = 0; i < 4; i++)
#pragma unroll
      for (int j = 0; j < 4; j++)
        acc[i][j] = __builtin_amdgcn_mfma_f32_16x16x32_bf16(af[i], bf[j], acc[i][j], 0, 0, 0);
  }

  float bi[4] = {0.f, 0.f, 0.f, 0.f};
  if (bias != nullptr) {
#pragma unroll
    for (int j = 0; j < 4; j++) bi[j] = bias[nBase + waveN * 64 + j * 16 + tm];
  }
  // C/D layout: col = lane&15, row = quad*4 + reg (m89/m91-verified)
#pragma unroll
  for (int i = 0; i < 4; i++) {
    int row0 = mBase + waveM * 64 + i * 16 + quad * 4;
#pragma unroll
    for (int j = 0; j < 4; j++) {
      int col = nBase + waveN * 64 + j * 16 + tm;
#pragma unroll
      for (int r = 0; r < 4; r++) {
        float v = acc[i][j][r] + bi[j];
        if (OUTF32)
          ((float*)Cv)[(size_t)(row0 + r) * N + col] = v;
        else
          ((u16*)Cv)[(size_t)(row0 + r) * N + col] = f2bf(v);
      }
    }
  }
}

// ---------------------------------------------------------------------------
// Cross-replica attention. One wave per (b, s, hk); 4 q-heads (h%HK==hk) share
// this K/V head. Lane t holds dims (t, t+64) = the RoPE rotation pair.
// QKV rows: (p*B+b)*S + s; cols [0,2048)=Q, [2048,2560)=K, [2560,3072)=V.
// O is written IN-PLACE over the Q columns of QKV (race-free per hk).
// cos/sin are fp32 (B, P, DH).
// ---------------------------------------------------------------------------
__global__ __launch_bounds__(64) void attn_xreplica(
    u16* __restrict__ QKV, const float* __restrict__ cosb,
    const float* __restrict__ sinb) {
  const int blk = blockIdx.x;
  const int s  = blk & (S_ - 1);
  const int hk = (blk >> 11) & (HK_ - 1);
  const int b  = blk >> 13;
  const int t  = threadIdx.x;  // 0..63
  const int d0 = t, d1 = t + 64;

  u16* rp[P_];
  float kr[P_][2], vv[P_][2], cs[P_][2], sn[P_][2];
#pragma unroll
  for (int p = 0; p < P_; p++) {
    rp[p] = QKV + ((size_t)((p * B_ + b) * S_ + s)) * NQKV;
    float c0 = cosb[(b * P_ + p) * DH_ + d0];
    float c1 = cosb[(b * P_ + p) * DH_ + d1];
    float s0 = sinb[(b * P_ + p) * DH_ + d0];
    float s1 = sinb[(b * P_ + p) * DH_ + d1];
    cs[p][0] = c0; cs[p][1] = c1; sn[p][0] = s0; sn[p][1] = s1;
    float k0 = bf2f(rp[p][H_ * DH_ + hk * DH_ + d0]);
    float k1 = bf2f(rp[p][H_ * DH_ + hk * DH_ + d1]);
    kr[p][0] = k0 * c0 - k1 * s0;   // rotate_half: d<64  -> -x[d+64]
    kr[p][1] = k1 * c1 + k0 * s1;   //              d>=64 ->  x[d-64]
    vv[p][0] = bf2f(rp[p][(H_ + HK_) * DH_ + hk * DH_ + d0]);
    vv[p][1] = bf2f(rp[p][(H_ + HK_) * DH_ + hk * DH_ + d1]);
  }

  const float scale = 0.08838834764831845f;  // DH^-0.5
#pragma unroll
  for (int hi = 0; hi < 4; hi++) {
    const int h = hk + hi * HK_;  // jnp.tile => k-head = h % HK
    float qr[P_][2];
#pragma unroll
    for (int p = 0; p < P_; p++) {
      float q0 = bf2f(rp[p][h * DH_ + d0]);
      float q1 = bf2f(rp[p][h * DH_ + d1]);
      qr[p][0] = q0 * cs[p][0] - q1 * sn[p][0];
      qr[p][1] = q1 * cs[p][1] + q0 * sn[p][1];
    }
    float sc[P_][P_];
#pragma unroll
    for (int pq = 0; pq < P_; pq++)
#pragma unroll
      for (int pk = 0; pk < P_; pk++) {
        float v = qr[pq][0] * kr[pk][0] + qr[pq][1] * kr[pk][1];
#pragma unroll
        for (int off = 32; off >= 1; off >>= 1) v += __shfl_xor(v, off, 64);
        sc[pq][pk] = v;
      }
#pragma unroll
    for (int pq = 0; pq < P_; pq++) {
      float x0 = sc[pq][0] * scale, x1 = sc[pq][1] * scale;
      float x2 = sc[pq][2] * scale, x3 = sc[pq][3] * scale;
      float m = fmaxf(fmaxf(x0, x1), fmaxf(x2, x3));
      float e0 = __expf(x0 - m), e1 = __expf(x1 - m);
      float e2 = __expf(x2 - m), e3 = __expf(x3 - m);
      float inv = 1.0f / (e0 + e1 + e2 + e3);
      float w0 = e0 * inv, w1 = e1 * inv, w2 = e2 * inv, w3 = e3 * inv;
      float o0 = w0 * vv[0][0] + w1 * vv[1][0] + w2 * vv[2][0] + w3 * vv[3][0];
      float o1 = w0 * vv[0][1] + w1 * vv[1][1] + w2 * vv[2][1] + w3 * vv[3][1];
      // in-place: O for (pq, b, s, h) over Q columns of row (pq*B+b, s)
      u16* orow = rp[pq] + h * DH_;
      orow[d0] = f2bf(o0);
      orow[d1] = f2bf(o1);
    }
  }
}

// ---------------------------------------------------------------------------
extern "C" void kernel_launch(void* const* d_in, const int* in_sizes, int n_in,
                              void* d_out, int out_size, void* d_ws, size_t ws_size,
                              hipStream_t stream) {
  const float* hs   = (const float*)d_in[0];
  const float* cosb = (const float*)d_in[1];
  const float* sinb = (const float*)d_in[2];
  const float* Wq   = (const float*)d_in[3];
  const float* bq   = (const float*)d_in[4];
  const float* Wk   = (const float*)d_in[5];
  const float* bk   = (const float*)d_in[6];
  const float* Wv   = (const float*)d_in[7];
  const float* bv   = (const float*)d_in[8];
  const float* Wo   = (const float*)d_in[9];

  // workspace layout, total ~121.7 MB
  u16*   WqkvT = (u16*)d_ws;                        // 3072 x 2048 bf16
  u16*   WoT   = WqkvT + (size_t)NQKV * K_;         // 2048 x 2048 bf16
  float* biasQ = (float*)(WoT + (size_t)D_ * K_);   // 3072 fp32 (+pad)
  u16*   QKV   = (u16*)(biasQ + 4096);              // 16384 x 3072 bf16 (O in-place)

  dim3 tb(32, 8);
  transpose_f32_bf16<<<dim3(64, 64), tb, 0, stream>>>(Wq, WqkvT, D_, H_ * DH_, 0, K_);
  transpose_f32_bf16<<<dim3(16, 64), tb, 0, stream>>>(Wk, WqkvT, D_, HK_ * DH_,
                                                      (size_t)(H_ * DH_) * K_, K_);
  transpose_f32_bf16<<<dim3(16, 64), tb, 0, stream>>>(Wv, WqkvT, D_, HK_ * DH_,
                                                      (size_t)((H_ + HK_) * DH_) * K_, K_);
  transpose_f32_bf16<<<dim3(64, 64), tb, 0, stream>>>(Wo, WoT, H_ * DH_, D_, 0, K_);
  build_bias<<<12, 256, 0, stream>>>(bq, bk, bv, biasQ);

  // QKV = hs @ [Wq|Wk|Wv] + bias   (A fp32 converted in staging; C bf16)
  gemm_bt<true, false><<<dim3(NQKV / 128, M_ / 128), 256, 0, stream>>>(
      (const void*)hs, K_, WqkvT, (void*)QKV, NQKV, K_, biasQ);

  // RoPE + 4x4 cross-replica attention, O written over Q columns
  attn_xreplica<<<B_ * HK_ * S_, 64, 0, stream>>>(QKV, cosb, sinb);

  // out = O @ Wo   (A = QKV's Q columns bf16, lda = 3072; C fp32 = d_out)
  gemm_bt<false, true><<<dim3(D_ / 128, M_ / 128), 256, 0, stream>>>(
      (const void*)QKV, NQKV, WoT, d_out, D_, K_, nullptr);
}